// Round 1
// baseline (731.986 us; speedup 1.0000x reference)
//
#include <hip/hip_runtime.h>
#include <math.h>

// Problem constants
#define NB   4
#define SEQ  1024
#define DMOD 512
#define NHD  8
#define DK   64

// ws float-offsets
// [0,64): c[d]
// [64,192): W[d*2+p]
// [256, +2M): Q   (B,H,S,64)
// [.., +6M):  K123 (B,H,S,3,64)  (K0|K1|K2 per row)
// [.., +2M): V    (B,H,S,64)
// [.., +2M): O2   (fc output + residual) (B,S,512)
#define Q_OFF   256
#define K_OFF   (256 + 2097152)
#define V_OFF   (256 + 2097152 + 6291456)
#define O2_OFF  (V_OFF + 2097152)

__global__ __launch_bounds__(64)
void prep_kernel(const float* __restrict__ rp_w1, const float* __restrict__ rp_b1,
                 const float* __restrict__ rp_w2, const float* __restrict__ rp_b2,
                 float* __restrict__ ws)
{
    int d = threadIdx.x;  // 0..63
    float w0 = 0.f, w1 = 0.f, cc = 0.f;
    for (int j = 0; j < 64; j++) {
        float r2 = rp_w2[d * 64 + j];
        w0 += r2 * rp_w1[j * 2 + 0];
        w1 += r2 * rp_w1[j * 2 + 1];
        cc += r2 * rp_b1[j];
    }
    ws[d] = cc + rp_b2[d];
    ws[64 + 2 * d + 0] = w0;
    ws[64 + 2 * d + 1] = w1;
}

// Tiled GEMM: Y[n,o] = sum_m X[n,m] * Wt[o,m], N=4096, O=512, M=512
// 64x64 tile per block, 256 threads, 4x4 micro-tile, k-chunk 16.
// MODE 0: write Q layout (B,H,S,64)
// MODE 1: write K123 (B,H,S,192) scaled by c / W0 / W1 (from wc)
// MODE 2: write V layout (B,H,S,64)
// MODE 3: write out[n*512+o] = acc + resid[n*512+o]
template<int MODE>
__global__ __launch_bounds__(256)
void gemm_nt(const float* __restrict__ X, const float* __restrict__ Wt,
             float* __restrict__ out, const float* __restrict__ wc,
             const float* __restrict__ resid)
{
    __shared__ float Xs[16][64];
    __shared__ float Ws[16][64];
    const int n0 = blockIdx.y * 64;
    const int o0 = blockIdx.x * 64;
    const int tid = threadIdx.x;
    const int ty = tid >> 4, tx = tid & 15;
    float acc[4][4] = {};
    for (int m0 = 0; m0 < 512; m0 += 16) {
        {
            int i  = tid >> 2;
            int t4 = (tid & 3) * 4;
            float4 xv = *(const float4*)&X[(n0 + i) * 512 + m0 + t4];
            Xs[t4 + 0][i] = xv.x; Xs[t4 + 1][i] = xv.y;
            Xs[t4 + 2][i] = xv.z; Xs[t4 + 3][i] = xv.w;
            float4 wv = *(const float4*)&Wt[(o0 + i) * 512 + m0 + t4];
            Ws[t4 + 0][i] = wv.x; Ws[t4 + 1][i] = wv.y;
            Ws[t4 + 2][i] = wv.z; Ws[t4 + 3][i] = wv.w;
        }
        __syncthreads();
        #pragma unroll
        for (int t = 0; t < 16; t++) {
            float4 xv = *(const float4*)&Xs[t][ty * 4];
            float4 wv = *(const float4*)&Ws[t][tx * 4];
            float xr[4] = {xv.x, xv.y, xv.z, xv.w};
            float wr[4] = {wv.x, wv.y, wv.z, wv.w};
            #pragma unroll
            for (int r = 0; r < 4; r++)
                #pragma unroll
                for (int c = 0; c < 4; c++)
                    acc[r][c] += xr[r] * wr[c];
        }
        __syncthreads();
    }
    #pragma unroll
    for (int r = 0; r < 4; r++) {
        int n = n0 + ty * 4 + r;
        #pragma unroll
        for (int c = 0; c < 4; c++) {
            int o = o0 + tx * 4 + c;
            float a = acc[r][c];
            if (MODE == 0 || MODE == 2) {
                int b = n >> 10, s = n & 1023, h = o >> 6, d = o & 63;
                out[(((b * NHD + h) << 10) + s) * 64 + d] = a;
            } else if (MODE == 1) {
                int b = n >> 10, s = n & 1023, h = o >> 6, d = o & 63;
                int base = ((((b * NHD + h) << 10) + s) * 192) + d;
                out[base]       = a * wc[d];
                out[base + 64]  = a * wc[64 + 2 * d + 0];
                out[base + 128] = a * wc[64 + 2 * d + 1];
            } else {
                out[n * 512 + o] = a + resid[n * 512 + o];
            }
        }
    }
}

// Scores: attn[bh,q,k] = (<Q,K0> + p0*<Q,K1> + p1*<Q,K2>) / 8
// grid (bh=32, ktile=16, qtile=16), 64x64 tile, full 64-d staged in LDS.
__global__ __launch_bounds__(256)
void score_kernel(const float* __restrict__ Q, const float* __restrict__ K123,
                  const float* __restrict__ pos, float* __restrict__ attn)
{
    __shared__ float Qs[64 * 64];      // [d][q]
    __shared__ float Ks[3 * 64 * 64];  // [j][d][k]
    const int bh = blockIdx.x;
    const int k0 = blockIdx.y * 64;
    const int q0 = blockIdx.z * 64;
    const int tid = threadIdx.x;

    for (int idx = tid; idx < 1024; idx += 256) {
        int d4 = (idx & 15) * 4;
        int qq = idx >> 4;
        float4 v = *(const float4*)&Q[((bh << 10) + q0 + qq) * 64 + d4];
        Qs[(d4 + 0) * 64 + qq] = v.x;
        Qs[(d4 + 1) * 64 + qq] = v.y;
        Qs[(d4 + 2) * 64 + qq] = v.z;
        Qs[(d4 + 3) * 64 + qq] = v.w;
    }
    for (int idx = tid; idx < 3072; idx += 256) {
        int d4 = (idx & 15) * 4;
        int j  = (idx >> 4) % 3;
        int kk = idx / 48;
        float4 v = *(const float4*)&K123[((bh << 10) + k0 + kk) * 192 + j * 64 + d4];
        Ks[(j * 64 + d4 + 0) * 64 + kk] = v.x;
        Ks[(j * 64 + d4 + 1) * 64 + kk] = v.y;
        Ks[(j * 64 + d4 + 2) * 64 + kk] = v.z;
        Ks[(j * 64 + d4 + 3) * 64 + kk] = v.w;
    }
    __syncthreads();

    const int ty = tid >> 4, tx = tid & 15;
    float a0[4][4] = {}, a1[4][4] = {}, a2[4][4] = {};
    for (int d = 0; d < 64; d++) {
        float4 qv  = *(const float4*)&Qs[d * 64 + ty * 4];
        float4 k0v = *(const float4*)&Ks[(0 * 64 + d) * 64 + tx * 4];
        float4 k1v = *(const float4*)&Ks[(1 * 64 + d) * 64 + tx * 4];
        float4 k2v = *(const float4*)&Ks[(2 * 64 + d) * 64 + tx * 4];
        float qr[4]  = {qv.x, qv.y, qv.z, qv.w};
        float r0[4]  = {k0v.x, k0v.y, k0v.z, k0v.w};
        float r1[4]  = {k1v.x, k1v.y, k1v.z, k1v.w};
        float r2[4]  = {k2v.x, k2v.y, k2v.z, k2v.w};
        #pragma unroll
        for (int r = 0; r < 4; r++)
            #pragma unroll
            for (int c = 0; c < 4; c++) {
                a0[r][c] += qr[r] * r0[c];
                a1[r][c] += qr[r] * r1[c];
                a2[r][c] += qr[r] * r2[c];
            }
    }
    #pragma unroll
    for (int r = 0; r < 4; r++) {
        int q = q0 + ty * 4 + r;
        #pragma unroll
        for (int c = 0; c < 4; c++) {
            int k = k0 + tx * 4 + c;
            float2 p = *(const float2*)&pos[(q * 1024 + k) * 2];
            float sc = (a0[r][c] + p.x * a1[r][c] + p.y * a2[r][c]) * 0.125f;
            attn[((bh << 10) + q) * 1024 + k] = sc;
        }
    }
}

__global__ __launch_bounds__(256)
void softmax_kernel(float* __restrict__ attn)
{
    const int row = blockIdx.x;
    const int tid = threadIdx.x;
    float4 x = *(float4*)&attn[row * 1024 + tid * 4];
    float mx = fmaxf(fmaxf(x.x, x.y), fmaxf(x.z, x.w));
    for (int off = 32; off; off >>= 1) mx = fmaxf(mx, __shfl_down(mx, off, 64));
    __shared__ float red[4];
    __shared__ float bc;
    int wave = tid >> 6, lane = tid & 63;
    if (lane == 0) red[wave] = mx;
    __syncthreads();
    if (tid == 0) bc = fmaxf(fmaxf(red[0], red[1]), fmaxf(red[2], red[3]));
    __syncthreads();
    mx = bc;
    x.x = expf(x.x - mx); x.y = expf(x.y - mx);
    x.z = expf(x.z - mx); x.w = expf(x.w - mx);
    float sm = x.x + x.y + x.z + x.w;
    for (int off = 32; off; off >>= 1) sm += __shfl_down(sm, off, 64);
    __syncthreads();
    if (lane == 0) red[wave] = sm;
    __syncthreads();
    if (tid == 0) bc = red[0] + red[1] + red[2] + red[3];
    __syncthreads();
    float inv = 1.0f / bc;
    x.x *= inv; x.y *= inv; x.z *= inv; x.w *= inv;
    *(float4*)&attn[row * 1024 + tid * 4] = x;
}

// O[b,q,h*64+d] = sum_k attn[bh,q,k] * V[bh,k,d]; grid (bh=32, qtile=16)
__global__ __launch_bounds__(256)
void pv_kernel(const float* __restrict__ attn, const float* __restrict__ V,
               float* __restrict__ O)
{
    __shared__ float Ps[32][64];  // [k][q]
    __shared__ float Vs[32][64];  // [k][d]
    const int bh = blockIdx.x;
    const int q0 = blockIdx.y * 64;
    const int tid = threadIdx.x;
    const int ty = tid >> 4, tx = tid & 15;
    float acc[4][4] = {};
    for (int k0 = 0; k0 < 1024; k0 += 32) {
        for (int idx = tid; idx < 512; idx += 256) {
            int t4 = (idx & 7) * 4;
            int qq = idx >> 3;
            float4 v = *(const float4*)&attn[((bh << 10) + q0 + qq) * 1024 + k0 + t4];
            Ps[t4 + 0][qq] = v.x; Ps[t4 + 1][qq] = v.y;
            Ps[t4 + 2][qq] = v.z; Ps[t4 + 3][qq] = v.w;
        }
        for (int idx = tid; idx < 512; idx += 256) {
            int d4 = (idx & 15) * 4;
            int t  = idx >> 4;
            float4 v = *(const float4*)&V[((bh << 10) + k0 + t) * 64 + d4];
            *(float4*)&Vs[t][d4] = v;
        }
        __syncthreads();
        #pragma unroll
        for (int t = 0; t < 32; t++) {
            float4 pv = *(const float4*)&Ps[t][ty * 4];
            float4 vv = *(const float4*)&Vs[t][tx * 4];
            float pr[4] = {pv.x, pv.y, pv.z, pv.w};
            float vr[4] = {vv.x, vv.y, vv.z, vv.w};
            #pragma unroll
            for (int r = 0; r < 4; r++)
                #pragma unroll
                for (int c = 0; c < 4; c++)
                    acc[r][c] += pr[r] * vr[c];
        }
        __syncthreads();
    }
    const int b = bh >> 3, h = bh & 7;
    #pragma unroll
    for (int r = 0; r < 4; r++) {
        int q = q0 + ty * 4 + r;
        #pragma unroll
        for (int c = 0; c < 4; c++) {
            int d = tx * 4 + c;
            O[((b << 10) + q) * 512 + h * 64 + d] = acc[r][c];
        }
    }
}

__global__ __launch_bounds__(256)
void ln_kernel(const float* __restrict__ X, const float* __restrict__ g,
               const float* __restrict__ bta, float* __restrict__ out)
{
    const int row = blockIdx.x;
    const int tid = threadIdx.x;
    float2 x = *(const float2*)&X[row * 512 + tid * 2];
    float s  = x.x + x.y;
    float s2 = x.x * x.x + x.y * x.y;
    for (int off = 32; off; off >>= 1) {
        s  += __shfl_down(s, off, 64);
        s2 += __shfl_down(s2, off, 64);
    }
    __shared__ float rs[4], rs2[4];
    __shared__ float mu_s, rstd_s;
    int wave = tid >> 6, lane = tid & 63;
    if (lane == 0) { rs[wave] = s; rs2[wave] = s2; }
    __syncthreads();
    if (tid == 0) {
        float S1 = rs[0] + rs[1] + rs[2] + rs[3];
        float S2 = rs2[0] + rs2[1] + rs2[2] + rs2[3];
        float mu = S1 * (1.0f / 512.0f);
        float var = S2 * (1.0f / 512.0f) - mu * mu;
        mu_s = mu;
        rstd_s = rsqrtf(var + 1e-6f);
    }
    __syncthreads();
    float mu = mu_s, rstd = rstd_s;
    float2 gv = *(const float2*)&g[tid * 2];
    float2 bv = *(const float2*)&bta[tid * 2];
    float2 o;
    o.x = (x.x - mu) * rstd * gv.x + bv.x;
    o.y = (x.y - mu) * rstd * gv.y + bv.y;
    *(float2*)&out[row * 512 + tid * 2] = o;
}

extern "C" void kernel_launch(void* const* d_in, const int* in_sizes, int n_in,
                              void* d_out, int out_size, void* d_ws, size_t ws_size,
                              hipStream_t stream)
{
    const float* q       = (const float*)d_in[0];
    const float* k       = (const float*)d_in[1];
    const float* v       = (const float*)d_in[2];
    const float* pos_mat = (const float*)d_in[3];
    const float* w_qs    = (const float*)d_in[4];
    const float* w_ks    = (const float*)d_in[5];
    const float* w_vs    = (const float*)d_in[6];
    const float* w_fc    = (const float*)d_in[7];
    const float* rp_w1   = (const float*)d_in[8];
    const float* rp_b1   = (const float*)d_in[9];
    const float* rp_w2   = (const float*)d_in[10];
    const float* rp_b2   = (const float*)d_in[11];
    const float* ln_g    = (const float*)d_in[12];
    const float* ln_b    = (const float*)d_in[13];

    float* ws   = (float*)d_ws;
    float* Qb   = ws + Q_OFF;
    float* Kb   = ws + K_OFF;
    float* Vb   = ws + V_OFF;
    float* O2   = ws + O2_OFF;

    float* out  = (float*)d_out;       // final (B,S,512); also temp O
    float* attn = out + 2097152;       // (B,H,S,S) logits -> probs

    prep_kernel<<<dim3(1), dim3(64), 0, stream>>>(rp_w1, rp_b1, rp_w2, rp_b2, ws);

    dim3 gp(8, 64);  // o-tiles, n-tiles
    gemm_nt<0><<<gp, 256, 0, stream>>>(q, w_qs, Qb, nullptr, nullptr);
    gemm_nt<1><<<gp, 256, 0, stream>>>(k, w_ks, Kb, ws, nullptr);
    gemm_nt<2><<<gp, 256, 0, stream>>>(v, w_vs, Vb, nullptr, nullptr);

    score_kernel<<<dim3(32, 16, 16), 256, 0, stream>>>(Qb, Kb, pos_mat, attn);
    softmax_kernel<<<dim3(32768), 256, 0, stream>>>(attn);
    pv_kernel<<<dim3(32, 16), 256, 0, stream>>>(attn, Vb, out);

    gemm_nt<3><<<gp, 256, 0, stream>>>(out, w_fc, O2, nullptr, q);
    ln_kernel<<<dim3(4096), 256, 0, stream>>>(O2, ln_g, ln_b, out);
}

// Round 4
// 526.714 us; speedup vs baseline: 1.3897x; 1.3897x over previous
//
#include <hip/hip_runtime.h>
#include <math.h>

// Problem constants
#define NB   4
#define SEQ  1024
#define DMOD 512
#define NHD  8
#define DK   64

typedef unsigned short ushort_t;
typedef __attribute__((ext_vector_type(8))) short bf16x8;
typedef __attribute__((ext_vector_type(4))) float f32x4;

// ws byte-offsets
// [0, 768):        wc  (c[64] then W[64][2])  fp32
// [1024, +4MB):    Qbf   (B,H,S,64)  bf16
// [.., +12MB):     K123bf (B,H,S,192) bf16
// [.., +8MB):      V fp32 (B,H,S,64)
// [.., +8MB):      O2 fp32 (B,S,512)
#define QBF_OFF  1024
#define KBF_OFF  (QBF_OFF + 4194304)
#define VF_OFF   (KBF_OFF + 12582912)
#define O2_OFF   (VF_OFF + 8388608)

__device__ inline ushort_t f2bf(float x) {
    unsigned u = __builtin_bit_cast(unsigned, x);
    unsigned r = (u + 0x7FFFu + ((u >> 16) & 1u)) >> 16;
    return (ushort_t)r;
}

__global__ __launch_bounds__(64)
void prep_kernel(const float* __restrict__ rp_w1, const float* __restrict__ rp_b1,
                 const float* __restrict__ rp_w2, const float* __restrict__ rp_b2,
                 float* __restrict__ ws)
{
    int d = threadIdx.x;  // 0..63
    float w0 = 0.f, w1 = 0.f, cc = 0.f;
    for (int j = 0; j < 64; j++) {
        float r2 = rp_w2[d * 64 + j];
        w0 += r2 * rp_w1[j * 2 + 0];
        w1 += r2 * rp_w1[j * 2 + 1];
        cc += r2 * rp_b1[j];
    }
    ws[d] = cc + rp_b2[d];
    ws[64 + 2 * d + 0] = w0;
    ws[64 + 2 * d + 1] = w1;
}

// Tiled GEMM: Y[n,o] = sum_m X[n,m] * Wt[o,m], N=4096, O=512, M=512
// MODE 0: write Q bf16 layout (B,H,S,64)
// MODE 1: write K123 bf16 (B,H,S,192) scaled by c / W0 / W1 (from wc)
// MODE 2: write V fp32 layout (B,H,S,64)
// MODE 3: write out fp32 [n*512+o] = acc + resid[n*512+o]
template<int MODE>
__global__ __launch_bounds__(256)
void gemm_nt(const float* __restrict__ X, const float* __restrict__ Wt,
             float* __restrict__ out, const float* __restrict__ wc = nullptr,
             const float* __restrict__ resid = nullptr,
             ushort_t* __restrict__ obf = nullptr)
{
    __shared__ float Xs[16][64];
    __shared__ float Ws[16][64];
    const int n0 = blockIdx.y * 64;
    const int o0 = blockIdx.x * 64;
    const int tid = threadIdx.x;
    const int ty = tid >> 4, tx = tid & 15;
    float acc[4][4] = {};
    for (int m0 = 0; m0 < 512; m0 += 16) {
        {
            int i  = tid >> 2;
            int t4 = (tid & 3) * 4;
            float4 xv = *(const float4*)&X[(n0 + i) * 512 + m0 + t4];
            Xs[t4 + 0][i] = xv.x; Xs[t4 + 1][i] = xv.y;
            Xs[t4 + 2][i] = xv.z; Xs[t4 + 3][i] = xv.w;
            float4 wv = *(const float4*)&Wt[(o0 + i) * 512 + m0 + t4];
            Ws[t4 + 0][i] = wv.x; Ws[t4 + 1][i] = wv.y;
            Ws[t4 + 2][i] = wv.z; Ws[t4 + 3][i] = wv.w;
        }
        __syncthreads();
        #pragma unroll
        for (int t = 0; t < 16; t++) {
            float4 xv = *(const float4*)&Xs[t][ty * 4];
            float4 wv = *(const float4*)&Ws[t][tx * 4];
            float xr[4] = {xv.x, xv.y, xv.z, xv.w};
            float wr[4] = {wv.x, wv.y, wv.z, wv.w};
            #pragma unroll
            for (int r = 0; r < 4; r++)
                #pragma unroll
                for (int c = 0; c < 4; c++)
                    acc[r][c] += xr[r] * wr[c];
        }
        __syncthreads();
    }
    #pragma unroll
    for (int r = 0; r < 4; r++) {
        int n = n0 + ty * 4 + r;
        #pragma unroll
        for (int c = 0; c < 4; c++) {
            int o = o0 + tx * 4 + c;
            float a = acc[r][c];
            if (MODE == 0) {
                int b = n >> 10, s = n & 1023, h = o >> 6, d = o & 63;
                obf[(((b * NHD + h) << 10) + s) * 64 + d] = f2bf(a);
            } else if (MODE == 1) {
                int b = n >> 10, s = n & 1023, h = o >> 6, d = o & 63;
                int base = ((((b * NHD + h) << 10) + s) * 192) + d;
                obf[base]       = f2bf(a * wc[d]);
                obf[base + 64]  = f2bf(a * wc[64 + 2 * d + 0]);
                obf[base + 128] = f2bf(a * wc[64 + 2 * d + 1]);
            } else if (MODE == 2) {
                int b = n >> 10, s = n & 1023, h = o >> 6, d = o & 63;
                out[(((b * NHD + h) << 10) + s) * 64 + d] = a;
            } else {
                out[n * 512 + o] = a + resid[n * 512 + o];
            }
        }
    }
}

// Scores via MFMA bf16: attn[bh,q,k] = (<Q,K0> + p0*<Q,K1> + p1*<Q,K2>) / 8
// grid (bh=32, ktile=16, qtile=16); 64x64 output tile; 4 waves, each wave
// handles a 16-row q-strip x all 4 k-subtiles, 3 accumulators each.
#define QPITCH 72
#define KPLANE (64 * QPITCH + 8)   // shift j-planes by 8 shorts (16B) to spread banks
__global__ __launch_bounds__(256)
void score_kernel(const ushort_t* __restrict__ Qbf, const ushort_t* __restrict__ Kbf,
                  const float* __restrict__ pos, float* __restrict__ attn)
{
    __shared__ ushort_t Qs[64 * QPITCH];
    __shared__ ushort_t Ks[3 * KPLANE];
    const int bh = blockIdx.x;
    const int k0 = blockIdx.y * 64;
    const int q0 = blockIdx.z * 64;
    const int tid = threadIdx.x;

    // stage Q tile: 64 rows x 64 bf16 (16B chunks)
    #pragma unroll
    for (int it = 0; it < 2; it++) {
        int idx = tid + it * 256;
        int row = idx >> 3, c8 = idx & 7;
        uint4 vv = *(const uint4*)&Qbf[((bh << 10) + q0 + row) * 64 + c8 * 8];
        *(uint4*)&Qs[row * QPITCH + c8 * 8] = vv;
    }
    // stage K tile: 64 rows x 192 bf16
    #pragma unroll
    for (int it = 0; it < 6; it++) {
        int idx = tid + it * 256;
        int row = idx / 24, c = idx % 24;  // c = j*8 + d8
        int j = c >> 3, d8 = c & 7;
        uint4 vv = *(const uint4*)&Kbf[((bh << 10) + k0 + row) * 192 + c * 8];
        *(uint4*)&Ks[j * KPLANE + row * QPITCH + d8 * 8] = vv;
    }
    __syncthreads();

    const int wave = tid >> 6, lane = tid & 63;
    const int m16 = lane & 15, g = lane >> 4;

    f32x4 acc[4][3] = {};  // [k-subtile][j]
    const ushort_t* qbase = &Qs[(wave * 16 + m16) * QPITCH + g * 8];
    #pragma unroll
    for (int kc = 0; kc < 2; kc++) {
        bf16x8 af = *(const bf16x8*)(qbase + kc * 32);
        #pragma unroll
        for (int tk = 0; tk < 4; tk++) {
            #pragma unroll
            for (int j = 0; j < 3; j++) {
                bf16x8 bfv = *(const bf16x8*)&Ks[j * KPLANE + (tk * 16 + m16) * QPITCH + kc * 32 + g * 8];
                acc[tk][j] = __builtin_amdgcn_mfma_f32_16x16x32_bf16(af, bfv, acc[tk][j], 0, 0, 0);
            }
        }
    }

    // epilogue: C layout col=lane&15, row=(lane>>4)*4+reg
    const int qrow = q0 + wave * 16 + g * 4;
    #pragma unroll
    for (int tk = 0; tk < 4; tk++) {
        int kcol = k0 + tk * 16 + m16;
        #pragma unroll
        for (int r = 0; r < 4; r++) {
            int q = qrow + r;
            float2 p = *(const float2*)&pos[(q * 1024 + kcol) * 2];
            float sc = (acc[tk][0][r] + p.x * acc[tk][1][r] + p.y * acc[tk][2][r]) * 0.125f;
            attn[((bh << 10) + q) * 1024 + kcol] = sc;
        }
    }
}

__global__ __launch_bounds__(256)
void softmax_kernel(float* __restrict__ attn)
{
    const int row = blockIdx.x;
    const int tid = threadIdx.x;
    float4 x = *(float4*)&attn[row * 1024 + tid * 4];
    float mx = fmaxf(fmaxf(x.x, x.y), fmaxf(x.z, x.w));
    for (int off = 32; off; off >>= 1) mx = fmaxf(mx, __shfl_down(mx, off, 64));
    __shared__ float red[4];
    __shared__ float bc;
    int wave = tid >> 6, lane = tid & 63;
    if (lane == 0) red[wave] = mx;
    __syncthreads();
    if (tid == 0) bc = fmaxf(fmaxf(red[0], red[1]), fmaxf(red[2], red[3]));
    __syncthreads();
    mx = bc;
    x.x = expf(x.x - mx); x.y = expf(x.y - mx);
    x.z = expf(x.z - mx); x.w = expf(x.w - mx);
    float sm = x.x + x.y + x.z + x.w;
    for (int off = 32; off; off >>= 1) sm += __shfl_down(sm, off, 64);
    __syncthreads();
    if (lane == 0) red[wave] = sm;
    __syncthreads();
    if (tid == 0) bc = red[0] + red[1] + red[2] + red[3];
    __syncthreads();
    float inv = 1.0f / bc;
    x.x *= inv; x.y *= inv; x.z *= inv; x.w *= inv;
    *(float4*)&attn[row * 1024 + tid * 4] = x;
}

// O[b,q,h*64+d] = sum_k attn[bh,q,k] * V[bh,k,d]; grid (bh=32, qtile=16)
__global__ __launch_bounds__(256)
void pv_kernel(const float* __restrict__ attn, const float* __restrict__ V,
               float* __restrict__ O)
{
    __shared__ float Ps[32][64];  // [k][q]
    __shared__ float Vs[32][64];  // [k][d]
    const int bh = blockIdx.x;
    const int q0 = blockIdx.y * 64;
    const int tid = threadIdx.x;
    const int ty = tid >> 4, tx = tid & 15;
    float acc[4][4] = {};
    for (int k0 = 0; k0 < 1024; k0 += 32) {
        for (int idx = tid; idx < 512; idx += 256) {
            int t4 = (idx & 7) * 4;
            int qq = idx >> 3;
            float4 v = *(const float4*)&attn[((bh << 10) + q0 + qq) * 1024 + k0 + t4];
            Ps[t4 + 0][qq] = v.x; Ps[t4 + 1][qq] = v.y;
            Ps[t4 + 2][qq] = v.z; Ps[t4 + 3][qq] = v.w;
        }
        for (int idx = tid; idx < 512; idx += 256) {
            int d4 = (idx & 15) * 4;
            int t  = idx >> 4;
            float4 v = *(const float4*)&V[((bh << 10) + k0 + t) * 64 + d4];
            *(float4*)&Vs[t][d4] = v;
        }
        __syncthreads();
        #pragma unroll
        for (int t = 0; t < 32; t++) {
            float4 pv = *(const float4*)&Ps[t][ty * 4];
            float4 vv = *(const float4*)&Vs[t][tx * 4];
            float pr[4] = {pv.x, pv.y, pv.z, pv.w};
            float vr[4] = {vv.x, vv.y, vv.z, vv.w};
            #pragma unroll
            for (int r = 0; r < 4; r++)
                #pragma unroll
                for (int c = 0; c < 4; c++)
                    acc[r][c] += pr[r] * vr[c];
        }
        __syncthreads();
    }
    const int b = bh >> 3, h = bh & 7;
    #pragma unroll
    for (int r = 0; r < 4; r++) {
        int q = q0 + ty * 4 + r;
        #pragma unroll
        for (int c = 0; c < 4; c++) {
            int d = tx * 4 + c;
            O[((b << 10) + q) * 512 + h * 64 + d] = acc[r][c];
        }
    }
}

__global__ __launch_bounds__(256)
void ln_kernel(const float* __restrict__ X, const float* __restrict__ g,
               const float* __restrict__ bta, float* __restrict__ out)
{
    const int row = blockIdx.x;
    const int tid = threadIdx.x;
    float2 x = *(const float2*)&X[row * 512 + tid * 2];
    float s  = x.x + x.y;
    float s2 = x.x * x.x + x.y * x.y;
    for (int off = 32; off; off >>= 1) {
        s  += __shfl_down(s, off, 64);
        s2 += __shfl_down(s2, off, 64);
    }
    __shared__ float rs[4], rs2[4];
    __shared__ float mu_s, rstd_s;
    int wave = tid >> 6, lane = tid & 63;
    if (lane == 0) { rs[wave] = s; rs2[wave] = s2; }
    __syncthreads();
    if (tid == 0) {
        float S1 = rs[0] + rs[1] + rs[2] + rs[3];
        float S2 = rs2[0] + rs2[1] + rs2[2] + rs2[3];
        float mu = S1 * (1.0f / 512.0f);
        float var = S2 * (1.0f / 512.0f) - mu * mu;
        mu_s = mu;
        rstd_s = rsqrtf(var + 1e-6f);
    }
    __syncthreads();
    float mu = mu_s, rstd = rstd_s;
    float2 gv = *(const float2*)&g[tid * 2];
    float2 bv = *(const float2*)&bta[tid * 2];
    float2 o;
    o.x = (x.x - mu) * rstd * gv.x + bv.x;
    o.y = (x.y - mu) * rstd * gv.y + bv.y;
    *(float2*)&out[row * 512 + tid * 2] = o;
}

extern "C" void kernel_launch(void* const* d_in, const int* in_sizes, int n_in,
                              void* d_out, int out_size, void* d_ws, size_t ws_size,
                              hipStream_t stream)
{
    const float* q       = (const float*)d_in[0];
    const float* k       = (const float*)d_in[1];
    const float* v       = (const float*)d_in[2];
    const float* pos_mat = (const float*)d_in[3];
    const float* w_qs    = (const float*)d_in[4];
    const float* w_ks    = (const float*)d_in[5];
    const float* w_vs    = (const float*)d_in[6];
    const float* w_fc    = (const float*)d_in[7];
    const float* rp_w1   = (const float*)d_in[8];
    const float* rp_b1   = (const float*)d_in[9];
    const float* rp_w2   = (const float*)d_in[10];
    const float* rp_b2   = (const float*)d_in[11];
    const float* ln_g    = (const float*)d_in[12];
    const float* ln_b    = (const float*)d_in[13];

    float*    ws  = (float*)d_ws;
    ushort_t* Qbf = (ushort_t*)((char*)d_ws + QBF_OFF);
    ushort_t* Kbf = (ushort_t*)((char*)d_ws + KBF_OFF);
    float*    Vf  = (float*)((char*)d_ws + VF_OFF);
    float*    O2  = (float*)((char*)d_ws + O2_OFF);

    float* out  = (float*)d_out;       // final (B,S,512); also temp O
    float* attn = out + 2097152;       // (B,H,S,S) logits -> probs

    prep_kernel<<<dim3(1), dim3(64), 0, stream>>>(rp_w1, rp_b1, rp_w2, rp_b2, ws);

    dim3 gp(8, 64);  // o-tiles, n-tiles
    gemm_nt<0><<<gp, 256, 0, stream>>>(q, w_qs, nullptr, nullptr, nullptr, Qbf);
    gemm_nt<1><<<gp, 256, 0, stream>>>(k, w_ks, nullptr, ws, nullptr, Kbf);
    gemm_nt<2><<<gp, 256, 0, stream>>>(v, w_vs, Vf, nullptr, nullptr, nullptr);

    score_kernel<<<dim3(32, 16, 16), 256, 0, stream>>>(Qbf, Kbf, pos_mat, attn);
    softmax_kernel<<<dim3(32768), 256, 0, stream>>>(attn);
    pv_kernel<<<dim3(32, 16), 256, 0, stream>>>(attn, Vf, out);

    gemm_nt<3><<<gp, 256, 0, stream>>>(out, w_fc, O2, nullptr, q, nullptr);
    ln_kernel<<<dim3(4096), 256, 0, stream>>>(O2, ln_g, ln_b, out);
}

// Round 5
// 345.287 us; speedup vs baseline: 2.1199x; 1.5254x over previous
//
#include <hip/hip_runtime.h>
#include <math.h>

// Problem constants
#define NB   4
#define SEQ  1024
#define DMOD 512
#define NHD  8
#define DK   64

typedef unsigned short ushort_t;
typedef __attribute__((ext_vector_type(8))) short bf16x8;
typedef __attribute__((ext_vector_type(4))) float f32x4;

// ---------------- workspace layout (bytes) ----------------
// WC:   [0, 1024)          c[64] then W[64][2] fp32
// XQ:   4 MB  bf16 of q     (aliased later: O2 fp32 8MB spans XQ+XK)
// XK:   4 MB  bf16 of k
// XV:   4 MB  bf16 of v     (aliased later: Obf bf16 4MB)
// WQ/WK/WV/WF: 512 KB each  bf16 weights
// QBF:  4 MB  Q   (B,H,S,64) bf16
// KBF: 12 MB  K123 (B,H,S,192) bf16
// VT:   4 MB  V^T (B*H, 64, S) bf16
#define XQ_OFF   1024
#define XK_OFF   (XQ_OFF + 4194304)
#define XV_OFF   (XK_OFF + 4194304)
#define WQ_OFF   (XV_OFF + 4194304)
#define WK_OFF   (WQ_OFF + 524288)
#define WV_OFF   (WK_OFF + 524288)
#define WF_OFF   (WV_OFF + 524288)
#define QBF_OFF  (WF_OFF + 524288)
#define KBF_OFF  (QBF_OFF + 4194304)
#define VT_OFF   (KBF_OFF + 12582912)
// aliases (stream-ordered safe):
#define O2_OFF   XQ_OFF   // fp32 8MB, written by fc after XQ/XK dead
#define OBF_OFF  XV_OFF   // bf16 4MB, written by pv after XV dead

__device__ inline ushort_t f2bf(float x) {
    unsigned u = __builtin_bit_cast(unsigned, x);
    unsigned r = (u + 0x7FFFu + ((u >> 16) & 1u)) >> 16;
    return (ushort_t)r;
}
__device__ inline unsigned pk2(float a, float b) {
    return (unsigned)f2bf(a) | ((unsigned)f2bf(b) << 16);
}

__global__ __launch_bounds__(64)
void prep_kernel(const float* __restrict__ rp_w1, const float* __restrict__ rp_b1,
                 const float* __restrict__ rp_w2, const float* __restrict__ rp_b2,
                 float* __restrict__ ws)
{
    int d = threadIdx.x;  // 0..63
    float w0 = 0.f, w1 = 0.f, cc = 0.f;
    for (int j = 0; j < 64; j++) {
        float r2 = rp_w2[d * 64 + j];
        w0 += r2 * rp_w1[j * 2 + 0];
        w1 += r2 * rp_w1[j * 2 + 1];
        cc += r2 * rp_b1[j];
    }
    ws[d] = cc + rp_b2[d];
    ws[64 + 2 * d + 0] = w0;
    ws[64 + 2 * d + 1] = w1;
}

// fp32 -> bf16 converters
__global__ __launch_bounds__(256)
void cvt3_kernel(const float* __restrict__ s0, const float* __restrict__ s1,
                 const float* __restrict__ s2, ushort_t* __restrict__ d0,
                 ushort_t* __restrict__ d1, ushort_t* __restrict__ d2)
{
    int t = blockIdx.x * 256 + threadIdx.x;
    const float* s = (blockIdx.y == 0) ? s0 : (blockIdx.y == 1) ? s1 : s2;
    ushort_t* d = (blockIdx.y == 0) ? d0 : (blockIdx.y == 1) ? d1 : d2;
    float4 v = *(const float4*)&s[t * 4];
    uint2 o = {pk2(v.x, v.y), pk2(v.z, v.w)};
    *(uint2*)&d[t * 4] = o;
}

__global__ __launch_bounds__(256)
void cvt4_kernel(const float* __restrict__ s0, const float* __restrict__ s1,
                 const float* __restrict__ s2, const float* __restrict__ s3,
                 ushort_t* __restrict__ d0, ushort_t* __restrict__ d1,
                 ushort_t* __restrict__ d2, ushort_t* __restrict__ d3)
{
    int t = blockIdx.x * 256 + threadIdx.x;
    const float* s = (blockIdx.y == 0) ? s0 : (blockIdx.y == 1) ? s1
                   : (blockIdx.y == 2) ? s2 : s3;
    ushort_t* d = (blockIdx.y == 0) ? d0 : (blockIdx.y == 1) ? d1
                : (blockIdx.y == 2) ? d2 : d3;
    float4 v = *(const float4*)&s[t * 4];
    uint2 o = {pk2(v.x, v.y), pk2(v.z, v.w)};
    *(uint2*)&d[t * 4] = o;
}

// MFMA NT GEMM: Y[n,o] = sum_m X[n,m]*Wt[o,m]; N=4096, O=512, M=512, bf16 in.
// 64x64 tile, 256 thr, 4 waves; wave w does n-strip w*16 x 4 o-subtiles.
// MODE 0: Qbf (B,H,S,64); MODE 1: K123 scaled; MODE 2: Vt (BH,64,S) transposed;
// MODE 3: fp32 out + resid.
#define GP 72
template<int MODE>
__global__ __launch_bounds__(256)
void mfma_gemm(const ushort_t* __restrict__ X, const ushort_t* __restrict__ Wt,
               ushort_t* __restrict__ obf, float* __restrict__ ofp,
               const float* __restrict__ wc, const float* __restrict__ resid)
{
    __shared__ ushort_t Xs[64 * GP];
    __shared__ ushort_t Ws[64 * GP];
    const int n0 = blockIdx.y * 64;
    const int o0 = blockIdx.x * 64;
    const int tid = threadIdx.x;
    const int wave = tid >> 6, lane = tid & 63;
    const int m16 = lane & 15, g = lane >> 4;

    f32x4 acc[4] = {};
    for (int m0 = 0; m0 < 512; m0 += 64) {
        #pragma unroll
        for (int it = 0; it < 2; it++) {
            int idx = tid + it * 256;
            int row = idx >> 3, c8 = (idx & 7) * 8;
            *(uint4*)&Xs[row * GP + c8] = *(const uint4*)&X[(n0 + row) * 512 + m0 + c8];
            *(uint4*)&Ws[row * GP + c8] = *(const uint4*)&Wt[(o0 + row) * 512 + m0 + c8];
        }
        __syncthreads();
        #pragma unroll
        for (int kc = 0; kc < 2; kc++) {
            bf16x8 a = *(const bf16x8*)&Xs[(wave * 16 + m16) * GP + kc * 32 + g * 8];
            #pragma unroll
            for (int to = 0; to < 4; to++) {
                bf16x8 b = *(const bf16x8*)&Ws[(to * 16 + m16) * GP + kc * 32 + g * 8];
                acc[to] = __builtin_amdgcn_mfma_f32_16x16x32_bf16(a, b, acc[to], 0, 0, 0);
            }
        }
        __syncthreads();
    }
    // epilogue: C row = n0 + wave*16 + g*4 + r ; col = o0 + to*16 + m16
    #pragma unroll
    for (int to = 0; to < 4; to++) {
        int o = o0 + to * 16 + m16;
        #pragma unroll
        for (int r = 0; r < 4; r++) {
            int n = n0 + wave * 16 + g * 4 + r;
            float a = acc[to][r];
            int b = n >> 10, s = n & 1023, h = o >> 6, d = o & 63;
            if (MODE == 0) {
                obf[(((b * NHD + h) << 10) + s) * 64 + d] = f2bf(a);
            } else if (MODE == 1) {
                int base = ((((b * NHD + h) << 10) + s) * 192) + d;
                obf[base]       = f2bf(a * wc[d]);
                obf[base + 64]  = f2bf(a * wc[64 + 2 * d + 0]);
                obf[base + 128] = f2bf(a * wc[64 + 2 * d + 1]);
            } else if (MODE == 2) {
                obf[((b * NHD + h) * 64 + d) * 1024 + s] = f2bf(a);
            } else {
                ofp[n * 512 + o] = a + resid[n * 512 + o];
            }
        }
    }
}

// Scores via MFMA bf16: attn[bh,q,k] = (<Q,K0> + p0*<Q,K1> + p1*<Q,K2>) / 8
#define QPITCH 72
#define KPLANE (64 * QPITCH + 8)
__global__ __launch_bounds__(256)
void score_kernel(const ushort_t* __restrict__ Qbf, const ushort_t* __restrict__ Kbf,
                  const float* __restrict__ pos, float* __restrict__ attn)
{
    __shared__ ushort_t Qs[64 * QPITCH];
    __shared__ ushort_t Ks[3 * KPLANE];
    const int bh = blockIdx.x;
    const int k0 = blockIdx.y * 64;
    const int q0 = blockIdx.z * 64;
    const int tid = threadIdx.x;

    #pragma unroll
    for (int it = 0; it < 2; it++) {
        int idx = tid + it * 256;
        int row = idx >> 3, c8 = idx & 7;
        uint4 vv = *(const uint4*)&Qbf[((bh << 10) + q0 + row) * 64 + c8 * 8];
        *(uint4*)&Qs[row * QPITCH + c8 * 8] = vv;
    }
    #pragma unroll
    for (int it = 0; it < 6; it++) {
        int idx = tid + it * 256;
        int row = idx / 24, c = idx % 24;
        int j = c >> 3, d8 = c & 7;
        uint4 vv = *(const uint4*)&Kbf[((bh << 10) + k0 + row) * 192 + c * 8];
        *(uint4*)&Ks[j * KPLANE + row * QPITCH + d8 * 8] = vv;
    }
    __syncthreads();

    const int wave = tid >> 6, lane = tid & 63;
    const int m16 = lane & 15, g = lane >> 4;

    f32x4 acc[4][3] = {};
    const ushort_t* qbase = &Qs[(wave * 16 + m16) * QPITCH + g * 8];
    #pragma unroll
    for (int kc = 0; kc < 2; kc++) {
        bf16x8 af = *(const bf16x8*)(qbase + kc * 32);
        #pragma unroll
        for (int tk = 0; tk < 4; tk++) {
            #pragma unroll
            for (int j = 0; j < 3; j++) {
                bf16x8 bfv = *(const bf16x8*)&Ks[j * KPLANE + (tk * 16 + m16) * QPITCH + kc * 32 + g * 8];
                acc[tk][j] = __builtin_amdgcn_mfma_f32_16x16x32_bf16(af, bfv, acc[tk][j], 0, 0, 0);
            }
        }
    }

    const int qrow = q0 + wave * 16 + g * 4;
    #pragma unroll
    for (int tk = 0; tk < 4; tk++) {
        int kcol = k0 + tk * 16 + m16;
        #pragma unroll
        for (int r = 0; r < 4; r++) {
            int q = qrow + r;
            float2 p = *(const float2*)&pos[(q * 1024 + kcol) * 2];
            float sc = (acc[tk][0][r] + p.x * acc[tk][1][r] + p.y * acc[tk][2][r]) * 0.125f;
            attn[((bh << 10) + q) * 1024 + kcol] = sc;
        }
    }
}

__global__ __launch_bounds__(256)
void softmax_kernel(float* __restrict__ attn)
{
    const int row = blockIdx.x;
    const int tid = threadIdx.x;
    float4 x = *(float4*)&attn[row * 1024 + tid * 4];
    float mx = fmaxf(fmaxf(x.x, x.y), fmaxf(x.z, x.w));
    for (int off = 32; off; off >>= 1) mx = fmaxf(mx, __shfl_down(mx, off, 64));
    __shared__ float red[4];
    __shared__ float bc;
    int wave = tid >> 6, lane = tid & 63;
    if (lane == 0) red[wave] = mx;
    __syncthreads();
    if (tid == 0) bc = fmaxf(fmaxf(red[0], red[1]), fmaxf(red[2], red[3]));
    __syncthreads();
    mx = bc;
    x.x = expf(x.x - mx); x.y = expf(x.y - mx);
    x.z = expf(x.z - mx); x.w = expf(x.w - mx);
    float sm = x.x + x.y + x.z + x.w;
    for (int off = 32; off; off >>= 1) sm += __shfl_down(sm, off, 64);
    __syncthreads();
    if (lane == 0) red[wave] = sm;
    __syncthreads();
    if (tid == 0) bc = red[0] + red[1] + red[2] + red[3];
    __syncthreads();
    float inv = 1.0f / bc;
    x.x *= inv; x.y *= inv; x.z *= inv; x.w *= inv;
    *(float4*)&attn[row * 1024 + tid * 4] = x;
}

// PV via MFMA: O[bh,q,d] = sum_k P[q,k] * V[k,d], P converted bf16 in staging,
// V read from pre-transposed Vt[bh][d][k]. Writes Obf bf16 (B,S,512).
__global__ __launch_bounds__(256)
void pv_mfma(const float* __restrict__ attn, const ushort_t* __restrict__ Vt,
             ushort_t* __restrict__ Obf)
{
    __shared__ ushort_t Ps[64 * GP];
    __shared__ ushort_t Vs[64 * GP];
    const int bh = blockIdx.x;
    const int q0 = blockIdx.y * 64;
    const int tid = threadIdx.x;
    const int wave = tid >> 6, lane = tid & 63;
    const int m16 = lane & 15, g = lane >> 4;

    f32x4 acc[4] = {};
    for (int k0 = 0; k0 < 1024; k0 += 64) {
        #pragma unroll
        for (int it = 0; it < 4; it++) {
            int idx = tid + it * 256;
            int row = idx >> 4, c4 = (idx & 15) * 4;
            float4 p = *(const float4*)&attn[((bh << 10) + q0 + row) * 1024 + k0 + c4];
            uint2 o = {pk2(p.x, p.y), pk2(p.z, p.w)};
            *(uint2*)&Ps[row * GP + c4] = o;
        }
        {
            int row = tid >> 2, c8 = (tid & 3) * 8;
            *(uint4*)&Vs[row * GP + c8] = *(const uint4*)&Vt[(bh * 64 + row) * 1024 + k0 + c8];
        }
        __syncthreads();
        #pragma unroll
        for (int kc = 0; kc < 2; kc++) {
            bf16x8 a = *(const bf16x8*)&Ps[(wave * 16 + m16) * GP + kc * 32 + g * 8];
            #pragma unroll
            for (int td = 0; td < 4; td++) {
                bf16x8 b = *(const bf16x8*)&Vs[(td * 16 + m16) * GP + kc * 32 + g * 8];
                acc[td] = __builtin_amdgcn_mfma_f32_16x16x32_bf16(a, b, acc[td], 0, 0, 0);
            }
        }
        __syncthreads();
    }
    const int b = bh >> 3, h = bh & 7;
    #pragma unroll
    for (int td = 0; td < 4; td++) {
        int d = td * 16 + m16;
        #pragma unroll
        for (int r = 0; r < 4; r++) {
            int q = q0 + wave * 16 + g * 4 + r;
            Obf[((b << 10) + q) * 512 + h * 64 + d] = f2bf(acc[td][r]);
        }
    }
}

__global__ __launch_bounds__(256)
void ln_kernel(const float* __restrict__ X, const float* __restrict__ g,
               const float* __restrict__ bta, float* __restrict__ out)
{
    const int row = blockIdx.x;
    const int tid = threadIdx.x;
    float2 x = *(const float2*)&X[row * 512 + tid * 2];
    float s  = x.x + x.y;
    float s2 = x.x * x.x + x.y * x.y;
    for (int off = 32; off; off >>= 1) {
        s  += __shfl_down(s, off, 64);
        s2 += __shfl_down(s2, off, 64);
    }
    __shared__ float rs[4], rs2[4];
    __shared__ float mu_s, rstd_s;
    int wave = tid >> 6, lane = tid & 63;
    if (lane == 0) { rs[wave] = s; rs2[wave] = s2; }
    __syncthreads();
    if (tid == 0) {
        float S1 = rs[0] + rs[1] + rs[2] + rs[3];
        float S2 = rs2[0] + rs2[1] + rs2[2] + rs2[3];
        float mu = S1 * (1.0f / 512.0f);
        float var = S2 * (1.0f / 512.0f) - mu * mu;
        mu_s = mu;
        rstd_s = rsqrtf(var + 1e-6f);
    }
    __syncthreads();
    float mu = mu_s, rstd = rstd_s;
    float2 gv = *(const float2*)&g[tid * 2];
    float2 bv = *(const float2*)&bta[tid * 2];
    float2 o;
    o.x = (x.x - mu) * rstd * gv.x + bv.x;
    o.y = (x.y - mu) * rstd * gv.y + bv.y;
    *(float2*)&out[row * 512 + tid * 2] = o;
}

extern "C" void kernel_launch(void* const* d_in, const int* in_sizes, int n_in,
                              void* d_out, int out_size, void* d_ws, size_t ws_size,
                              hipStream_t stream)
{
    const float* q       = (const float*)d_in[0];
    const float* k       = (const float*)d_in[1];
    const float* v       = (const float*)d_in[2];
    const float* pos_mat = (const float*)d_in[3];
    const float* w_qs    = (const float*)d_in[4];
    const float* w_ks    = (const float*)d_in[5];
    const float* w_vs    = (const float*)d_in[6];
    const float* w_fc    = (const float*)d_in[7];
    const float* rp_w1   = (const float*)d_in[8];
    const float* rp_b1   = (const float*)d_in[9];
    const float* rp_w2   = (const float*)d_in[10];
    const float* rp_b2   = (const float*)d_in[11];
    const float* ln_g    = (const float*)d_in[12];
    const float* ln_b    = (const float*)d_in[13];

    char* wsb = (char*)d_ws;
    float*    wc  = (float*)d_ws;
    ushort_t* XQ  = (ushort_t*)(wsb + XQ_OFF);
    ushort_t* XK  = (ushort_t*)(wsb + XK_OFF);
    ushort_t* XV  = (ushort_t*)(wsb + XV_OFF);
    ushort_t* WQ  = (ushort_t*)(wsb + WQ_OFF);
    ushort_t* WK  = (ushort_t*)(wsb + WK_OFF);
    ushort_t* WV  = (ushort_t*)(wsb + WV_OFF);
    ushort_t* WF  = (ushort_t*)(wsb + WF_OFF);
    ushort_t* Qbf = (ushort_t*)(wsb + QBF_OFF);
    ushort_t* Kbf = (ushort_t*)(wsb + KBF_OFF);
    ushort_t* Vt  = (ushort_t*)(wsb + VT_OFF);
    float*    O2  = (float*)(wsb + O2_OFF);     // aliases XQ+XK (dead by then)
    ushort_t* Obf = (ushort_t*)(wsb + OBF_OFF); // aliases XV (dead by then)

    float* out  = (float*)d_out;       // final (B,S,512)
    float* attn = out + 2097152;       // (B,H,S,S) logits -> probs

    prep_kernel<<<dim3(1), dim3(64), 0, stream>>>(rp_w1, rp_b1, rp_w2, rp_b2, wc);

    cvt3_kernel<<<dim3(2048, 3), 256, 0, stream>>>(q, k, v, XQ, XK, XV);
    cvt4_kernel<<<dim3(256, 4), 256, 0, stream>>>(w_qs, w_ks, w_vs, w_fc, WQ, WK, WV, WF);

    dim3 gp(8, 64);  // o-tiles, n-tiles
    mfma_gemm<0><<<gp, 256, 0, stream>>>(XQ, WQ, Qbf, nullptr, nullptr, nullptr);
    mfma_gemm<1><<<gp, 256, 0, stream>>>(XK, WK, Kbf, nullptr, wc, nullptr);
    mfma_gemm<2><<<gp, 256, 0, stream>>>(XV, WV, Vt, nullptr, nullptr, nullptr);

    score_kernel<<<dim3(32, 16, 16), 256, 0, stream>>>(Qbf, Kbf, pos_mat, attn);
    softmax_kernel<<<dim3(32768), 256, 0, stream>>>(attn);
    pv_mfma<<<dim3(32, 16), 256, 0, stream>>>(attn, Vt, Obf);

    mfma_gemm<3><<<gp, 256, 0, stream>>>(Obf, WF, nullptr, O2, nullptr, q);
    ln_kernel<<<dim3(4096), 256, 0, stream>>>(O2, ln_g, ln_b, out);
}

// Round 6
// 327.973 us; speedup vs baseline: 2.2318x; 1.0528x over previous
//
#include <hip/hip_runtime.h>
#include <math.h>

// Problem constants
#define NB   4
#define SEQ  1024
#define DMOD 512
#define NHD  8
#define DK   64

typedef unsigned short ushort_t;
typedef __attribute__((ext_vector_type(8))) short bf16x8;
typedef __attribute__((ext_vector_type(4))) float f32x4;

// ---------------- workspace layout (bytes) ----------------
#define XQ_OFF   1024
#define XK_OFF   (XQ_OFF + 4194304)
#define XV_OFF   (XK_OFF + 4194304)
#define WQ_OFF   (XV_OFF + 4194304)
#define WK_OFF   (WQ_OFF + 524288)
#define WV_OFF   (WK_OFF + 524288)
#define WF_OFF   (WV_OFF + 524288)
#define QBF_OFF  (WF_OFF + 524288)
#define KBF_OFF  (QBF_OFF + 4194304)
#define VT_OFF   (KBF_OFF + 12582912)
// aliases (stream-ordered safe):
#define O2_OFF   XQ_OFF   // fp32 8MB, written by fc after XQ/XK dead
#define OBF_OFF  XV_OFF   // bf16 4MB, written by fused attn after XV dead

__device__ inline ushort_t f2bf(float x) {
    unsigned u = __builtin_bit_cast(unsigned, x);
    unsigned r = (u + 0x7FFFu + ((u >> 16) & 1u)) >> 16;
    return (ushort_t)r;
}
__device__ inline unsigned pk2(float a, float b) {
    return (unsigned)f2bf(a) | ((unsigned)f2bf(b) << 16);
}

__global__ __launch_bounds__(64)
void prep_kernel(const float* __restrict__ rp_w1, const float* __restrict__ rp_b1,
                 const float* __restrict__ rp_w2, const float* __restrict__ rp_b2,
                 float* __restrict__ ws)
{
    int d = threadIdx.x;
    float w0 = 0.f, w1 = 0.f, cc = 0.f;
    for (int j = 0; j < 64; j++) {
        float r2 = rp_w2[d * 64 + j];
        w0 += r2 * rp_w1[j * 2 + 0];
        w1 += r2 * rp_w1[j * 2 + 1];
        cc += r2 * rp_b1[j];
    }
    ws[d] = cc + rp_b2[d];
    ws[64 + 2 * d + 0] = w0;
    ws[64 + 2 * d + 1] = w1;
}

__global__ __launch_bounds__(256)
void cvt3_kernel(const float* __restrict__ s0, const float* __restrict__ s1,
                 const float* __restrict__ s2, ushort_t* __restrict__ d0,
                 ushort_t* __restrict__ d1, ushort_t* __restrict__ d2)
{
    int t = blockIdx.x * 256 + threadIdx.x;
    const float* s = (blockIdx.y == 0) ? s0 : (blockIdx.y == 1) ? s1 : s2;
    ushort_t* d = (blockIdx.y == 0) ? d0 : (blockIdx.y == 1) ? d1 : d2;
    float4 v = *(const float4*)&s[t * 4];
    uint2 o = {pk2(v.x, v.y), pk2(v.z, v.w)};
    *(uint2*)&d[t * 4] = o;
}

__global__ __launch_bounds__(256)
void cvt4_kernel(const float* __restrict__ s0, const float* __restrict__ s1,
                 const float* __restrict__ s2, const float* __restrict__ s3,
                 ushort_t* __restrict__ d0, ushort_t* __restrict__ d1,
                 ushort_t* __restrict__ d2, ushort_t* __restrict__ d3)
{
    int t = blockIdx.x * 256 + threadIdx.x;
    const float* s = (blockIdx.y == 0) ? s0 : (blockIdx.y == 1) ? s1
                   : (blockIdx.y == 2) ? s2 : s3;
    ushort_t* d = (blockIdx.y == 0) ? d0 : (blockIdx.y == 1) ? d1
                : (blockIdx.y == 2) ? d2 : d3;
    float4 v = *(const float4*)&s[t * 4];
    uint2 o = {pk2(v.x, v.y), pk2(v.z, v.w)};
    *(uint2*)&d[t * 4] = o;
}

// MFMA NT GEMM: Y[n,o] = sum_m X[n,m]*Wt[o,m]; N=4096, O=512, M=512, bf16 in.
#define GP 72
template<int MODE>
__global__ __launch_bounds__(256)
void mfma_gemm(const ushort_t* __restrict__ X, const ushort_t* __restrict__ Wt,
               ushort_t* __restrict__ obf, float* __restrict__ ofp,
               const float* __restrict__ wc, const float* __restrict__ resid)
{
    __shared__ ushort_t Xs[64 * GP];
    __shared__ ushort_t Ws[64 * GP];
    const int n0 = blockIdx.y * 64;
    const int o0 = blockIdx.x * 64;
    const int tid = threadIdx.x;
    const int wave = tid >> 6, lane = tid & 63;
    const int m16 = lane & 15, g = lane >> 4;

    f32x4 acc[4] = {};
    for (int m0 = 0; m0 < 512; m0 += 64) {
        #pragma unroll
        for (int it = 0; it < 2; it++) {
            int idx = tid + it * 256;
            int row = idx >> 3, c8 = (idx & 7) * 8;
            *(uint4*)&Xs[row * GP + c8] = *(const uint4*)&X[(n0 + row) * 512 + m0 + c8];
            *(uint4*)&Ws[row * GP + c8] = *(const uint4*)&Wt[(o0 + row) * 512 + m0 + c8];
        }
        __syncthreads();
        #pragma unroll
        for (int kc = 0; kc < 2; kc++) {
            bf16x8 a = *(const bf16x8*)&Xs[(wave * 16 + m16) * GP + kc * 32 + g * 8];
            #pragma unroll
            for (int to = 0; to < 4; to++) {
                bf16x8 b = *(const bf16x8*)&Ws[(to * 16 + m16) * GP + kc * 32 + g * 8];
                acc[to] = __builtin_amdgcn_mfma_f32_16x16x32_bf16(a, b, acc[to], 0, 0, 0);
            }
        }
        __syncthreads();
    }
    #pragma unroll
    for (int to = 0; to < 4; to++) {
        int o = o0 + to * 16 + m16;
        #pragma unroll
        for (int r = 0; r < 4; r++) {
            int n = n0 + wave * 16 + g * 4 + r;
            float a = acc[to][r];
            int b = n >> 10, s = n & 1023, h = o >> 6, d = o & 63;
            if (MODE == 0) {
                obf[(((b * NHD + h) << 10) + s) * 64 + d] = f2bf(a);
            } else if (MODE == 1) {
                int base = ((((b * NHD + h) << 10) + s) * 192) + d;
                obf[base]       = f2bf(a * wc[d]);
                obf[base + 64]  = f2bf(a * wc[64 + 2 * d + 0]);
                obf[base + 128] = f2bf(a * wc[64 + 2 * d + 1]);
            } else if (MODE == 2) {
                obf[((b * NHD + h) * 64 + d) * 1024 + s] = f2bf(a);
            } else {
                ofp[n * 512 + o] = a + resid[n * 512 + o];
            }
        }
    }
}

// ---------------------------------------------------------------------------
// Fused score + softmax + PV (flash-style, two-pass; numerically identical to
// the separate pipeline: scores recomputed in pass 2, exp/normalize in fp32,
// PV uses bf16-rounded probs exactly as the old pv kernel did).
// grid (bh=32, qtile=16). LDS ~54KB -> 2 blocks/CU, 512 blocks fully resident.
// ---------------------------------------------------------------------------
#define QPITCH 72
#define KPLANE (64 * QPITCH + 8)
__global__ __launch_bounds__(256)
void fused_attn(const ushort_t* __restrict__ Qbf, const ushort_t* __restrict__ Kbf,
                const float* __restrict__ pos, const ushort_t* __restrict__ Vt,
                float* __restrict__ attn, ushort_t* __restrict__ Obf)
{
    __shared__ ushort_t Qs[64 * QPITCH];
    __shared__ ushort_t Ks[3 * KPLANE];
    __shared__ ushort_t Vs[64 * QPITCH];
    __shared__ ushort_t Ps[64 * QPITCH];
    const int bh = blockIdx.x;
    const int q0 = blockIdx.y * 64;
    const int tid = threadIdx.x;
    const int wave = tid >> 6, lane = tid & 63;
    const int m16 = lane & 15, g = lane >> 4;

    // stage Q tile once
    #pragma unroll
    for (int it = 0; it < 2; it++) {
        int idx = tid + it * 256;
        int row = idx >> 3, c8 = (idx & 7) * 8;
        *(uint4*)&Qs[row * QPITCH + c8] = *(const uint4*)&Qbf[((bh << 10) + q0 + row) * 64 + c8];
    }
    __syncthreads();

    const ushort_t* qbase = &Qs[(wave * 16 + m16) * QPITCH + g * 8];
    float m[4] = {-3.0e38f, -3.0e38f, -3.0e38f, -3.0e38f};
    float l[4] = {0.f, 0.f, 0.f, 0.f};

    // ---------------- pass 1: online max & sum ----------------
    for (int k0 = 0; k0 < 1024; k0 += 64) {
        #pragma unroll
        for (int it = 0; it < 6; it++) {
            int idx = tid + it * 256;
            int row = idx / 24, c = idx % 24;
            int j = c >> 3, d8 = (c & 7) * 8;
            *(uint4*)&Ks[j * KPLANE + row * QPITCH + d8] =
                *(const uint4*)&Kbf[((bh << 10) + k0 + row) * 192 + c * 8];
        }
        __syncthreads();

        f32x4 sc[4][3] = {};
        #pragma unroll
        for (int kc = 0; kc < 2; kc++) {
            bf16x8 af = *(const bf16x8*)(qbase + kc * 32);
            #pragma unroll
            for (int tk = 0; tk < 4; tk++)
                #pragma unroll
                for (int j = 0; j < 3; j++) {
                    bf16x8 bfv = *(const bf16x8*)&Ks[j * KPLANE + (tk * 16 + m16) * QPITCH + kc * 32 + g * 8];
                    sc[tk][j] = __builtin_amdgcn_mfma_f32_16x16x32_bf16(af, bfv, sc[tk][j], 0, 0, 0);
                }
        }

        #pragma unroll
        for (int r = 0; r < 4; r++) {
            int q = q0 + wave * 16 + g * 4 + r;
            float s4[4];
            #pragma unroll
            for (int tk = 0; tk < 4; tk++) {
                float2 pp = *(const float2*)&pos[(q * 1024 + k0 + tk * 16 + m16) * 2];
                s4[tk] = (sc[tk][0][r] + pp.x * sc[tk][1][r] + pp.y * sc[tk][2][r]) * 0.125f;
            }
            float tm = fmaxf(fmaxf(s4[0], s4[1]), fmaxf(s4[2], s4[3]));
            #pragma unroll
            for (int msk = 1; msk < 16; msk <<= 1) tm = fmaxf(tm, __shfl_xor(tm, msk, 64));
            float nm = fmaxf(m[r], tm);
            float ps = expf(s4[0] - nm) + expf(s4[1] - nm) + expf(s4[2] - nm) + expf(s4[3] - nm);
            #pragma unroll
            for (int msk = 1; msk < 16; msk <<= 1) ps += __shfl_xor(ps, msk, 64);
            l[r] = l[r] * expf(m[r] - nm) + ps;
            m[r] = nm;
        }
        __syncthreads();
    }
    float inv_l[4];
    #pragma unroll
    for (int r = 0; r < 4; r++) inv_l[r] = 1.0f / l[r];

    // ---------------- pass 2: probs write + PV ----------------
    f32x4 ao[4] = {};
    for (int k0 = 0; k0 < 1024; k0 += 64) {
        #pragma unroll
        for (int it = 0; it < 6; it++) {
            int idx = tid + it * 256;
            int row = idx / 24, c = idx % 24;
            int j = c >> 3, d8 = (c & 7) * 8;
            *(uint4*)&Ks[j * KPLANE + row * QPITCH + d8] =
                *(const uint4*)&Kbf[((bh << 10) + k0 + row) * 192 + c * 8];
        }
        #pragma unroll
        for (int it = 0; it < 2; it++) {
            int idx = tid + it * 256;
            int row = idx >> 3, c8 = (idx & 7) * 8;
            *(uint4*)&Vs[row * QPITCH + c8] = *(const uint4*)&Vt[(bh * 64 + row) * 1024 + k0 + c8];
        }
        __syncthreads();

        f32x4 sc[4][3] = {};
        #pragma unroll
        for (int kc = 0; kc < 2; kc++) {
            bf16x8 af = *(const bf16x8*)(qbase + kc * 32);
            #pragma unroll
            for (int tk = 0; tk < 4; tk++)
                #pragma unroll
                for (int j = 0; j < 3; j++) {
                    bf16x8 bfv = *(const bf16x8*)&Ks[j * KPLANE + (tk * 16 + m16) * QPITCH + kc * 32 + g * 8];
                    sc[tk][j] = __builtin_amdgcn_mfma_f32_16x16x32_bf16(af, bfv, sc[tk][j], 0, 0, 0);
                }
        }

        #pragma unroll
        for (int r = 0; r < 4; r++) {
            int q = q0 + wave * 16 + g * 4 + r;
            #pragma unroll
            for (int tk = 0; tk < 4; tk++) {
                float2 pp = *(const float2*)&pos[(q * 1024 + k0 + tk * 16 + m16) * 2];
                float s = (sc[tk][0][r] + pp.x * sc[tk][1][r] + pp.y * sc[tk][2][r]) * 0.125f;
                float p = expf(s - m[r]) * inv_l[r];
                attn[((bh << 10) + q) * 1024 + k0 + tk * 16 + m16] = p;
                Ps[(wave * 16 + g * 4 + r) * QPITCH + tk * 16 + m16] = f2bf(p);
            }
        }
        __syncthreads();

        #pragma unroll
        for (int kc = 0; kc < 2; kc++) {
            bf16x8 a = *(const bf16x8*)&Ps[(wave * 16 + m16) * QPITCH + kc * 32 + g * 8];
            #pragma unroll
            for (int td = 0; td < 4; td++) {
                bf16x8 b = *(const bf16x8*)&Vs[(td * 16 + m16) * QPITCH + kc * 32 + g * 8];
                ao[td] = __builtin_amdgcn_mfma_f32_16x16x32_bf16(a, b, ao[td], 0, 0, 0);
            }
        }
        __syncthreads();
    }

    const int b = bh >> 3, h = bh & 7;
    #pragma unroll
    for (int td = 0; td < 4; td++) {
        int d = td * 16 + m16;
        #pragma unroll
        for (int r = 0; r < 4; r++) {
            int q = q0 + wave * 16 + g * 4 + r;
            Obf[((b << 10) + q) * 512 + h * 64 + d] = f2bf(ao[td][r]);
        }
    }
}

__global__ __launch_bounds__(256)
void ln_kernel(const float* __restrict__ X, const float* __restrict__ g,
               const float* __restrict__ bta, float* __restrict__ out)
{
    const int row = blockIdx.x;
    const int tid = threadIdx.x;
    float2 x = *(const float2*)&X[row * 512 + tid * 2];
    float s  = x.x + x.y;
    float s2 = x.x * x.x + x.y * x.y;
    for (int off = 32; off; off >>= 1) {
        s  += __shfl_down(s, off, 64);
        s2 += __shfl_down(s2, off, 64);
    }
    __shared__ float rs[4], rs2[4];
    __shared__ float mu_s, rstd_s;
    int wave = tid >> 6, lane = tid & 63;
    if (lane == 0) { rs[wave] = s; rs2[wave] = s2; }
    __syncthreads();
    if (tid == 0) {
        float S1 = rs[0] + rs[1] + rs[2] + rs[3];
        float S2 = rs2[0] + rs2[1] + rs2[2] + rs2[3];
        float mu = S1 * (1.0f / 512.0f);
        float var = S2 * (1.0f / 512.0f) - mu * mu;
        mu_s = mu;
        rstd_s = rsqrtf(var + 1e-6f);
    }
    __syncthreads();
    float mu = mu_s, rstd = rstd_s;
    float2 gv = *(const float2*)&g[tid * 2];
    float2 bv = *(const float2*)&bta[tid * 2];
    float2 o;
    o.x = (x.x - mu) * rstd * gv.x + bv.x;
    o.y = (x.y - mu) * rstd * gv.y + bv.y;
    *(float2*)&out[row * 512 + tid * 2] = o;
}

extern "C" void kernel_launch(void* const* d_in, const int* in_sizes, int n_in,
                              void* d_out, int out_size, void* d_ws, size_t ws_size,
                              hipStream_t stream)
{
    const float* q       = (const float*)d_in[0];
    const float* k       = (const float*)d_in[1];
    const float* v       = (const float*)d_in[2];
    const float* pos_mat = (const float*)d_in[3];
    const float* w_qs    = (const float*)d_in[4];
    const float* w_ks    = (const float*)d_in[5];
    const float* w_vs    = (const float*)d_in[6];
    const float* w_fc    = (const float*)d_in[7];
    const float* rp_w1   = (const float*)d_in[8];
    const float* rp_b1   = (const float*)d_in[9];
    const float* rp_w2   = (const float*)d_in[10];
    const float* rp_b2   = (const float*)d_in[11];
    const float* ln_g    = (const float*)d_in[12];
    const float* ln_b    = (const float*)d_in[13];

    char* wsb = (char*)d_ws;
    float*    wc  = (float*)d_ws;
    ushort_t* XQ  = (ushort_t*)(wsb + XQ_OFF);
    ushort_t* XK  = (ushort_t*)(wsb + XK_OFF);
    ushort_t* XV  = (ushort_t*)(wsb + XV_OFF);
    ushort_t* WQ  = (ushort_t*)(wsb + WQ_OFF);
    ushort_t* WK  = (ushort_t*)(wsb + WK_OFF);
    ushort_t* WV  = (ushort_t*)(wsb + WV_OFF);
    ushort_t* WF  = (ushort_t*)(wsb + WF_OFF);
    ushort_t* Qbf = (ushort_t*)(wsb + QBF_OFF);
    ushort_t* Kbf = (ushort_t*)(wsb + KBF_OFF);
    ushort_t* Vt  = (ushort_t*)(wsb + VT_OFF);
    float*    O2  = (float*)(wsb + O2_OFF);
    ushort_t* Obf = (ushort_t*)(wsb + OBF_OFF);

    float* out  = (float*)d_out;       // final (B,S,512)
    float* attn = out + 2097152;       // (B,H,S,S) probs

    prep_kernel<<<dim3(1), dim3(64), 0, stream>>>(rp_w1, rp_b1, rp_w2, rp_b2, wc);

    cvt3_kernel<<<dim3(2048, 3), 256, 0, stream>>>(q, k, v, XQ, XK, XV);
    cvt4_kernel<<<dim3(256, 4), 256, 0, stream>>>(w_qs, w_ks, w_vs, w_fc, WQ, WK, WV, WF);

    dim3 gp(8, 64);
    mfma_gemm<0><<<gp, 256, 0, stream>>>(XQ, WQ, Qbf, nullptr, nullptr, nullptr);
    mfma_gemm<1><<<gp, 256, 0, stream>>>(XK, WK, Kbf, nullptr, wc, nullptr);
    mfma_gemm<2><<<gp, 256, 0, stream>>>(XV, WV, Vt, nullptr, nullptr, nullptr);

    fused_attn<<<dim3(32, 16), 256, 0, stream>>>(Qbf, Kbf, pos_mat, Vt, attn, Obf);

    mfma_gemm<3><<<gp, 256, 0, stream>>>(Obf, WF, nullptr, O2, nullptr, q);
    ln_kernel<<<dim3(4096), 256, 0, stream>>>(O2, ln_g, ln_b, out);
}